// Round 5
// baseline (407.148 us; speedup 1.0000x reference)
//
#include <hip/hip_runtime.h>

// Problem constants (B, T, IN, H, OUT) = (256, 128, 128, 256, 128)
// External tensors f32; internal MFMA in bf16 with f32 accumulate; gx
// workspace bf16 PRE-SCALED by log2e (r,z gates) / 2*log2e (n gate) so the
// gate math needs no multiplies before exp2.
#define B_   256
#define T_   128
#define IN_  128
#define H_   256
#define H3_  768
#define OUT_ 128

#define L2E  1.4426950408889634f

typedef unsigned short u16;
typedef u16   u16x4  __attribute__((ext_vector_type(4)));
typedef u16   u16x8  __attribute__((ext_vector_type(8)));
typedef __bf16 bf16x8 __attribute__((ext_vector_type(8)));
typedef float f32x4  __attribute__((ext_vector_type(4)));

__device__ __forceinline__ float bf2f(u16 u) {
  unsigned int v = ((unsigned int)u) << 16;
  return __builtin_bit_cast(float, v);
}
__device__ __forceinline__ u16 f2bf(float f) {        // RNE (off hot path)
  unsigned int u = __builtin_bit_cast(unsigned int, f);
  u += 0x7fffu + ((u >> 16) & 1u);
  return (u16)(u >> 16);
}
__device__ __forceinline__ u16 f2bf_fast(float f) {   // round-half-up
  unsigned int u = __builtin_bit_cast(unsigned int, f);
  return (u16)((u + 0x8000u) >> 16);
}
__device__ __forceinline__ f32x4 mfma16(bf16x8 a, bf16x8 b, f32x4 c) {
  return __builtin_amdgcn_mfma_f32_16x16x32_bf16(a, b, c, 0, 0, 0);
}
__device__ __forceinline__ float exp2f_(float x) {
#if __has_builtin(__builtin_amdgcn_exp2f)
  return __builtin_amdgcn_exp2f(x);
#else
  return __builtin_exp2f(x);
#endif
}
__device__ __forceinline__ float rcp_(float x) { return __builtin_amdgcn_rcpf(x); }

// async global->LDS 16B: LDS dest is wave-uniform base + lane*16
typedef const __attribute__((address_space(1))) unsigned int* gas_p;
typedef __attribute__((address_space(3))) unsigned int* las_p;
__device__ __forceinline__ void dma16(const u16* g, u16* l) {
  __builtin_amdgcn_global_load_lds((gas_p)(const void*)g, (las_p)(void*)l, 16, 0, 0);
}

// ---------------------------------------------------------------------------
// Kernel 1: Wx (f32, 128 x 768) -> WxT (bf16, 768 x 128), unscaled
__global__ __launch_bounds__(256) void wx_transpose(const float* __restrict__ Wx,
                                                    u16* __restrict__ WxT) {
  int o = blockIdx.x * 256 + threadIdx.x;       // 0..98303
  int n = o >> 7, k = o & 127;
  WxT[o] = f2bf(Wx[(size_t)k * H3_ + n]);
}

// ---------------------------------------------------------------------------
// Kernel 2: gx[t*B+b][n] = bf16( (x[b,t,:]@Wx[:,n] + bx[n] + (n<512?bh[n]:0)) * sc )
// sc = L2E for r/z gates (n<512), 2*L2E for n gate. M=32768, N=768, K=128.
// Tile 128(M) x 192(N), 512 threads (8 waves as 2Mx4N).
__global__ __launch_bounds__(512) void gx_gemm(const float* __restrict__ x,
                                               const u16* __restrict__ WxT,
                                               const float* __restrict__ bx,
                                               const float* __restrict__ bh,
                                               u16* __restrict__ gxw) {
  __shared__ __align__(16) u16 As[128][136];  // +8 pad
  __shared__ __align__(16) u16 Bs[192][136];
  const int mt = blockIdx.x;                  // 0..255
  const int n0 = blockIdx.y * 192;            // 0,192,384,576
  const int m0 = mt * 128;
  const int t  = mt >> 1;
  const int brow0 = (mt & 1) * 128;
  const int tid = threadIdx.x;
  const int w = tid >> 6, lane = tid & 63, quad = lane >> 4, r = lane & 15;
  const int wm = w >> 2, wn = w & 3;          // 2 x 4 wave grid

  {  // A tile: 128 rows x 128 cols, f32 -> bf16
    int row = tid >> 2;
    int colc = (tid & 3) * 32;
    const float* s = x + ((size_t)(brow0 + row) * T_ + t) * IN_ + colc;
    #pragma unroll
    for (int c4 = 0; c4 < 8; ++c4) {
      f32x4 v = *(const f32x4*)(s + c4 * 4);
      u16x4 b;
      b[0] = f2bf(v[0]); b[1] = f2bf(v[1]); b[2] = f2bf(v[2]); b[3] = f2bf(v[3]);
      *(u16x4*)&As[row][colc + c4 * 4] = b;
    }
  }
  {  // B tile [n][k] from WxT: 192 x 128 u16
    #pragma unroll
    for (int i = 0; i < 6; ++i) {
      int idx = tid + i * 512;                // 0..3071
      int row = idx >> 4, col8 = (idx & 15) * 8;
      *(u16x8*)&Bs[row][col8] = *(const u16x8*)(WxT + (size_t)(n0 + row) * IN_ + col8);
    }
  }
  __syncthreads();

  f32x4 acc[4][3];
  #pragma unroll
  for (int i = 0; i < 4; ++i)
    #pragma unroll
    for (int j = 0; j < 3; ++j)
      acc[i][j] = (f32x4){0.f, 0.f, 0.f, 0.f};

  #pragma unroll
  for (int kk = 0; kk < 4; ++kk) {
    bf16x8 a[4];
    #pragma unroll
    for (int m2 = 0; m2 < 4; ++m2)
      a[m2] = *(const bf16x8*)&As[wm * 64 + m2 * 16 + r][kk * 32 + quad * 8];
    #pragma unroll
    for (int n2 = 0; n2 < 3; ++n2) {
      bf16x8 b = *(const bf16x8*)&Bs[wn * 48 + n2 * 16 + r][kk * 32 + quad * 8];
      #pragma unroll
      for (int m2 = 0; m2 < 4; ++m2)
        acc[m2][n2] = mfma16(a[m2], b, acc[m2][n2]);
    }
  }

  #pragma unroll
  for (int m2 = 0; m2 < 4; ++m2)
    #pragma unroll
    for (int n2 = 0; n2 < 3; ++n2) {
      int n = n0 + wn * 48 + n2 * 16 + r;              // C col = lane&15
      float sc = (n < 512) ? L2E : (2.f * L2E);
      float bias = bx[n] + (n < 512 ? bh[n] : 0.f);
      #pragma unroll
      for (int e = 0; e < 4; ++e) {                    // C row = quad*4 + e
        int mrow = wm * 64 + m2 * 16 + quad * 4 + e;
        gxw[(size_t)(m0 + mrow) * H3_ + n] = f2bf((acc[m2][n2][e] + bias) * sc);
      }
    }
}

// ---------------------------------------------------------------------------
// Kernel 3: the scan. 96 blocks x 512 threads, 8 rows per block (2x the CUs).
// Full Wh as per-lane MFMA A-fragments (192 VGPRs, prescaled). Per step:
//   MFMA (h_bf[p], rows via r&7) -> gh_lds (r<8 lanes)   | B1
//   global_load_lds gx(t+1) -> gx_flat[1-p] (async)
//   epilogue redistributed: thread (w=row, lane) does 4 gate-triples,
//     writes h_bf[1-p]                                    | B2 (drains DMA)
__global__ __launch_bounds__(512, 2) void cru_scan(const float* __restrict__ hid,
                                                   const float* __restrict__ Wh,
                                                   const float* __restrict__ bh,
                                                   const u16* __restrict__ gx,
                                                   float* __restrict__ hT) {
  __shared__ __align__(16) u16   h_bf[2][8][264];     // +8 pad, 8.4 KB
  __shared__ __align__(16) u16   gx_flat[2][6144];    // NO pad (DMA layout), 24 KB
  __shared__ __align__(16) float gh_lds[3][8][264];   // +8 pad, 25.3 KB
  __shared__ float bhn_lds[256];

  const int bid = blockIdx.x;           // 96 blocks
  const int c   = bid >> 5;             // component 0..2
  const int b0  = (bid & 31) << 3;      // batch row group of 8
  const int tid = threadIdx.x;
  const int w = tid >> 6, lane = tid & 63, quad = lane >> 4, r = lane & 15;

  // init h: thread (w=row, lane) owns h[w][lane*4..+3]
  const int col0 = lane * 4;
  f32x4 h_reg = *(const f32x4*)(hid + ((size_t)(c * 256 + b0 + w)) * 256 + col0);
  {
    u16x4 hb;
    #pragma unroll
    for (int e = 0; e < 4; ++e) hb[e] = f2bf(h_reg[e]);
    *(u16x4*)&h_bf[0][w][col0] = hb;
  }
  if (tid < 256) bhn_lds[tid] = bh[512 + tid] * (2.f * L2E);

  // preload gx tile for t=0 into gx_flat[0] (async DMA, drained at barrier)
  {
    const u16* base = gx + (size_t)b0 * H3_;
    dma16(base + (size_t)(w * 64 + lane) * 8, &gx_flat[0][w * 512]);
    if (w < 4)
      dma16(base + (size_t)(512 + w * 64 + lane) * 8, &gx_flat[0][(512 + w * 64) * 8]);
  }

  // One-time Wh^T A-fragment gather (prescaled):
  // frag[g][s][kk][j] = Wh[kk*32+quad*8+j][n] * sc,  n = g*256 + w*32 + s*16 + r
  bf16x8 bfr[3][2][8];
  #pragma unroll
  for (int g = 0; g < 3; ++g) {
    const float sgw = (g < 2) ? L2E : (2.f * L2E);
    #pragma unroll
    for (int s = 0; s < 2; ++s) {
      const int n = g * 256 + w * 32 + s * 16 + r;
      const float* p = Wh + (size_t)(quad * 8) * H3_ + n;
      #pragma unroll
      for (int kk = 0; kk < 8; ++kk) {
        u16x8 tmp;
        #pragma unroll
        for (int j = 0; j < 8; ++j)
          tmp[j] = f2bf(p[(size_t)(kk * 32 + j) * H3_] * sgw);
        bfr[g][s][kk] = __builtin_bit_cast(bf16x8, tmp);
      }
    }
  }

  __syncthreads();

  for (int t = 0; t < T_; ++t) {
    const int p = t & 1;

    // A) gh^T = Wh^T * h^T (B-frag rows via r&7: rows 8..15 duplicate 0..7,
    //    their D-columns are discarded)
    f32x4 acc[3][2];
    #pragma unroll
    for (int g = 0; g < 3; ++g)
      #pragma unroll
      for (int s = 0; s < 2; ++s)
        acc[g][s] = (f32x4){0.f, 0.f, 0.f, 0.f};

    #pragma unroll
    for (int kk = 0; kk < 8; ++kk) {
      bf16x8 hfrag = *(const bf16x8*)&h_bf[p][r & 7][kk * 32 + quad * 8];
      #pragma unroll
      for (int g = 0; g < 3; ++g)
        #pragma unroll
        for (int s = 0; s < 2; ++s)
          acc[g][s] = mfma16(bfr[g][s][kk], hfrag, acc[g][s]);
    }

    // write gh tile: D[row=quad*4+e][col=r] = gh[batch=r][w*32+s*16+quad*4+e]
    if (r < 8) {
      #pragma unroll
      for (int g = 0; g < 3; ++g)
        #pragma unroll
        for (int s = 0; s < 2; ++s)
          *(f32x4*)&gh_lds[g][r][w * 32 + s * 16 + quad * 4] = acc[g][s];
    }
    __syncthreads();  // B1: gh visible; t's gx DMA (issued last step) done

    // B) async-prefetch gx for t+1 into gx_flat[1-p]; drains at B2
    {
      const int tn = (t + 1 < T_) ? t + 1 : t;
      const u16* base = gx + ((size_t)tn * 256 + b0) * H3_;
      dma16(base + (size_t)(w * 64 + lane) * 8, &gx_flat[1 - p][w * 512]);
      if (w < 4)
        dma16(base + (size_t)(512 + w * 64 + lane) * 8,
              &gx_flat[1 - p][(512 + w * 64) * 8]);
    }

    // C) epilogue, redistributed: thread (w=row, lane) does cols col0..col0+3
    {
      f32x4 gr = *(const f32x4*)&gh_lds[0][w][col0];
      f32x4 gz = *(const f32x4*)&gh_lds[1][w][col0];
      f32x4 gn = *(const f32x4*)&gh_lds[2][w][col0];
      u16x4 xr4 = *(const u16x4*)&gx_flat[p][w * 768 + col0];
      u16x4 xz4 = *(const u16x4*)&gx_flat[p][w * 768 + 256 + col0];
      u16x4 xn4 = *(const u16x4*)&gx_flat[p][w * 768 + 512 + col0];
      f32x4 bh4 = *(const f32x4*)&bhn_lds[col0];
      u16x4 hw;
      #pragma unroll
      for (int e = 0; e < 4; ++e) {
        float sr = rcp_(1.f + exp2f_(-(bf2f(xr4[e]) + gr[e])));   // sigmoid
        float sz = rcp_(1.f + exp2f_(-(bf2f(xz4[e]) + gz[e])));
        float nv = bf2f(xn4[e]) + sr * (gn[e] + bh4[e]);          // pre-scaled 2*L2E
        float u  = exp2f_(-nv);
        float nn = fmaf(2.f, rcp_(1.f + u), -1.f);                // tanh, inf-safe
        float hv = nn + sz * (h_reg[e] - nn);
        h_reg[e] = hv;
        hw[e] = f2bf_fast(hv);
      }
      *(u16x4*)&h_bf[1 - p][w][col0] = hw;
    }
    __syncthreads();  // B2: h ready; DMA for t+1 drained
  }

  *(f32x4*)(hT + ((size_t)(c * 256 + b0 + w)) * 256 + col0) = h_reg;
}

// ---------------------------------------------------------------------------
// Kernel 4: out[b] = elu(sum_c hT[c,b,:] @ Wf + bf); feature[c,:] = mean_b hT
__global__ __launch_bounds__(128) void finalize(const float* __restrict__ hT,
                                                const float* __restrict__ Wf,
                                                const float* __restrict__ bfv,
                                                float* __restrict__ out) {
  __shared__ float hsum[256];
  const int bid = blockIdx.x, tid = threadIdx.x;
  if (bid < 256) {
    const int b = bid;
    for (int k = tid; k < 256; k += 128)
      hsum[k] = hT[((size_t)(0 * 256 + b)) * 256 + k]
              + hT[((size_t)(1 * 256 + b)) * 256 + k]
              + hT[((size_t)(2 * 256 + b)) * 256 + k];
    __syncthreads();
    float acc = bfv[tid];
    #pragma unroll 8
    for (int k = 0; k < 256; ++k)
      acc = fmaf(hsum[k], Wf[(size_t)k * OUT_ + tid], acc);
    float rv = acc > 0.f ? acc : (__expf(acc) - 1.f);
    out[b * OUT_ + tid] = rv;
  } else {
    const int idx = bid - 256;                 // 0..5
    const int c = idx >> 1, j = ((idx & 1) << 7) + tid;
    float sum = 0.f;
    #pragma unroll 4
    for (int b = 0; b < 256; ++b)
      sum += hT[((size_t)(c * 256 + b)) * 256 + j];
    out[B_ * OUT_ + c * 256 + j] = sum * (1.f / 256.f);
  }
}

// ---------------------------------------------------------------------------
extern "C" void kernel_launch(void* const* d_in, const int* in_sizes, int n_in,
                              void* d_out, int out_size, void* d_ws, size_t ws_size,
                              hipStream_t stream) {
  const float* x   = (const float*)d_in[0];
  const float* hid = (const float*)d_in[1];
  const float* Wx  = (const float*)d_in[2];
  const float* bx  = (const float*)d_in[3];
  const float* Wh  = (const float*)d_in[4];
  const float* bh  = (const float*)d_in[5];
  const float* Wf  = (const float*)d_in[6];
  const float* bf_ = (const float*)d_in[7];
  float* out = (float*)d_out;

  char* ws = (char*)d_ws;
  u16* WxT   = (u16*)ws;                                   // 768*128 bf16 = 192 KiB
  u16* gxw   = (u16*)(ws + (1 << 18));                     // 128*256*768 bf16 = 48 MiB
  float* hTw = (float*)(ws + (1 << 18) + (size_t)T_ * B_ * H3_ * 2);  // 3*256*256 f32

  wx_transpose<<<384, 256, 0, stream>>>(Wx, WxT);
  gx_gemm<<<dim3(256, 4), 512, 0, stream>>>(x, WxT, bx, bh, gxw);
  cru_scan<<<96, 512, 0, stream>>>(hid, Wh, bh, gxw, hTw);
  finalize<<<262, 128, 0, stream>>>(hTw, Wf, bf_, out);
}

// Round 6
// 348.926 us; speedup vs baseline: 1.1669x; 1.1669x over previous
//
#include <hip/hip_runtime.h>

// Problem constants (B, T, IN, H, OUT) = (256, 128, 128, 256, 128)
// External tensors f32; internal MFMA in bf16 with f32 accumulate; gx
// workspace bf16 PRE-SCALED by log2e (r,z gates) / 2*log2e (n gate) so the
// gate math needs no multiplies before exp2.
#define B_   256
#define T_   128
#define IN_  128
#define H_   256
#define H3_  768
#define OUT_ 128

#define L2E  1.4426950408889634f

typedef unsigned short u16;
typedef u16   u16x4  __attribute__((ext_vector_type(4)));
typedef u16   u16x8  __attribute__((ext_vector_type(8)));
typedef __bf16 bf16x8 __attribute__((ext_vector_type(8)));
typedef float f32x4  __attribute__((ext_vector_type(4)));

__device__ __forceinline__ float bf2f(u16 u) {
  unsigned int v = ((unsigned int)u) << 16;
  return __builtin_bit_cast(float, v);
}
__device__ __forceinline__ u16 f2bf(float f) {        // RNE (off hot path)
  unsigned int u = __builtin_bit_cast(unsigned int, f);
  u += 0x7fffu + ((u >> 16) & 1u);
  return (u16)(u >> 16);
}
__device__ __forceinline__ u16 f2bf_fast(float f) {   // round-half-up
  unsigned int u = __builtin_bit_cast(unsigned int, f);
  return (u16)((u + 0x8000u) >> 16);
}
__device__ __forceinline__ f32x4 mfma16(bf16x8 a, bf16x8 b, f32x4 c) {
  return __builtin_amdgcn_mfma_f32_16x16x32_bf16(a, b, c, 0, 0, 0);
}
__device__ __forceinline__ float exp2f_(float x) {
#if __has_builtin(__builtin_amdgcn_exp2f)
  return __builtin_amdgcn_exp2f(x);
#else
  return __builtin_exp2f(x);
#endif
}
__device__ __forceinline__ float rcp_(float x) { return __builtin_amdgcn_rcpf(x); }

// ---------------------------------------------------------------------------
// Kernel 1: Wx (f32, 128 x 768) -> WxT (bf16, 768 x 128), unscaled
__global__ __launch_bounds__(256) void wx_transpose(const float* __restrict__ Wx,
                                                    u16* __restrict__ WxT) {
  int o = blockIdx.x * 256 + threadIdx.x;       // 0..98303
  int n = o >> 7, k = o & 127;
  WxT[o] = f2bf(Wx[(size_t)k * H3_ + n]);
}

// ---------------------------------------------------------------------------
// Kernel 2: gx[t*B+b][n] = bf16( (x[b,t,:]@Wx[:,n] + bx[n] + (n<512?bh[n]:0)) * sc )
// sc = L2E for r/z gates (n<512), 2*L2E for n gate. M=32768, N=768, K=128.
// Tile 128(M) x 192(N), 512 threads (8 waves as 2Mx4N).
__global__ __launch_bounds__(512) void gx_gemm(const float* __restrict__ x,
                                               const u16* __restrict__ WxT,
                                               const float* __restrict__ bx,
                                               const float* __restrict__ bh,
                                               u16* __restrict__ gxw) {
  __shared__ __align__(16) u16 As[128][136];  // +8 pad
  __shared__ __align__(16) u16 Bs[192][136];
  const int mt = blockIdx.x;                  // 0..255
  const int n0 = blockIdx.y * 192;            // 0,192,384,576
  const int m0 = mt * 128;
  const int t  = mt >> 1;
  const int brow0 = (mt & 1) * 128;
  const int tid = threadIdx.x;
  const int w = tid >> 6, lane = tid & 63, quad = lane >> 4, r = lane & 15;
  const int wm = w >> 2, wn = w & 3;          // 2 x 4 wave grid

  {  // A tile: 128 rows x 128 cols, f32 -> bf16
    int row = tid >> 2;
    int colc = (tid & 3) * 32;
    const float* s = x + ((size_t)(brow0 + row) * T_ + t) * IN_ + colc;
    #pragma unroll
    for (int c4 = 0; c4 < 8; ++c4) {
      f32x4 v = *(const f32x4*)(s + c4 * 4);
      u16x4 b;
      b[0] = f2bf(v[0]); b[1] = f2bf(v[1]); b[2] = f2bf(v[2]); b[3] = f2bf(v[3]);
      *(u16x4*)&As[row][colc + c4 * 4] = b;
    }
  }
  {  // B tile [n][k] from WxT: 192 x 128 u16
    #pragma unroll
    for (int i = 0; i < 6; ++i) {
      int idx = tid + i * 512;                // 0..3071
      int row = idx >> 4, col8 = (idx & 15) * 8;
      *(u16x8*)&Bs[row][col8] = *(const u16x8*)(WxT + (size_t)(n0 + row) * IN_ + col8);
    }
  }
  __syncthreads();

  f32x4 acc[4][3];
  #pragma unroll
  for (int i = 0; i < 4; ++i)
    #pragma unroll
    for (int j = 0; j < 3; ++j)
      acc[i][j] = (f32x4){0.f, 0.f, 0.f, 0.f};

  #pragma unroll
  for (int kk = 0; kk < 4; ++kk) {
    bf16x8 a[4];
    #pragma unroll
    for (int m2 = 0; m2 < 4; ++m2)
      a[m2] = *(const bf16x8*)&As[wm * 64 + m2 * 16 + r][kk * 32 + quad * 8];
    #pragma unroll
    for (int n2 = 0; n2 < 3; ++n2) {
      bf16x8 b = *(const bf16x8*)&Bs[wn * 48 + n2 * 16 + r][kk * 32 + quad * 8];
      #pragma unroll
      for (int m2 = 0; m2 < 4; ++m2)
        acc[m2][n2] = mfma16(a[m2], b, acc[m2][n2]);
    }
  }

  #pragma unroll
  for (int m2 = 0; m2 < 4; ++m2)
    #pragma unroll
    for (int n2 = 0; n2 < 3; ++n2) {
      int n = n0 + wn * 48 + n2 * 16 + r;              // C col = lane&15
      float sc = (n < 512) ? L2E : (2.f * L2E);
      float bias = bx[n] + (n < 512 ? bh[n] : 0.f);
      #pragma unroll
      for (int e = 0; e < 4; ++e) {                    // C row = quad*4 + e
        int mrow = wm * 64 + m2 * 16 + quad * 4 + e;
        gxw[(size_t)(m0 + mrow) * H3_ + n] = f2bf((acc[m2][n2][e] + bias) * sc);
      }
    }
}

// ---------------------------------------------------------------------------
// Kernel 3: the scan. 96 blocks x 512 threads, 8 batch rows per block.
// Full Wh as per-lane MFMA A-fragments (192 VGPRs, prescaled), register
// residency FORCED via amdgpu_waves_per_eu(2,2) (round-5 spill post-mortem:
// __launch_bounds__(512,2) clamped to 128 VGPR and spilled all 768 B of
// fragments to scratch -> 40 MB WRITE_SIZE, LLC-bound).
// Per step:
//   issue gx loads (3 x u16x4 regs, this thread's own epilogue slice)
//   MFMA (h_bf via r&7) -> gh_lds (r<8 lanes)          | B1
//   epilogue: thread (w=batch row, lane) does 4 gate-triples from gx regs +
//     gh_lds + bhn regs, writes h_bf (single buffer OK: B1 ordered reads)
//                                                       | B2
__global__ __launch_bounds__(512)
__attribute__((amdgpu_waves_per_eu(2, 2)))
void cru_scan(const float* __restrict__ hid,
              const float* __restrict__ Wh,
              const float* __restrict__ bh,
              const u16* __restrict__ gx,
              float* __restrict__ hT) {
  __shared__ __align__(16) u16   h_bf[8][264];        // +8 pad, 4.1 KB
  __shared__ __align__(16) float gh_lds[3][8][264];   // +8 pad, 25.3 KB

  const int bid = blockIdx.x;           // 96 blocks
  const int c   = bid >> 5;             // component 0..2
  const int b0  = (bid & 31) << 3;      // batch row group of 8
  const int tid = threadIdx.x;
  const int w = tid >> 6, lane = tid & 63, quad = lane >> 4, r = lane & 15;

  // thread (w = batch row 0..7, lane) owns h[w][col0..col0+3]
  const int col0 = lane * 4;
  f32x4 h_reg = *(const f32x4*)(hid + ((size_t)(c * 256 + b0 + w)) * 256 + col0);
  {
    u16x4 hb;
    #pragma unroll
    for (int e = 0; e < 4; ++e) hb[e] = f2bf(h_reg[e]);
    *(u16x4*)&h_bf[w][col0] = hb;
  }
  f32x4 bhn;                            // n-gate bh, prescaled (mult. by r gate)
  {
    f32x4 bv = *(const f32x4*)(bh + 512 + col0);
    #pragma unroll
    for (int e = 0; e < 4; ++e) bhn[e] = bv[e] * (2.f * L2E);
  }

  // One-time Wh^T A-fragment gather (prescaled):
  // frag[g][s][kk][j] = Wh[kk*32+quad*8+j][n] * sc,  n = g*256 + w*32 + s*16 + r
  bf16x8 bfr[3][2][8];
  #pragma unroll
  for (int g = 0; g < 3; ++g) {
    const float sgw = (g < 2) ? L2E : (2.f * L2E);
    #pragma unroll
    for (int s = 0; s < 2; ++s) {
      const int n = g * 256 + w * 32 + s * 16 + r;
      const float* p = Wh + (size_t)(quad * 8) * H3_ + n;
      #pragma unroll
      for (int kk = 0; kk < 8; ++kk) {
        u16x8 tmp;
        #pragma unroll
        for (int j = 0; j < 8; ++j)
          tmp[j] = f2bf(p[(size_t)(kk * 32 + j) * H3_] * sgw);
        bfr[g][s][kk] = __builtin_bit_cast(bf16x8, tmp);
      }
    }
  }

  // per-thread gx source: row (b0+w), cols col0..+3 of each gate
  const u16* gx_row = gx + ((size_t)b0 + w) * H3_;

  __syncthreads();

  for (int t = 0; t < T_; ++t) {
    // A) issue THIS step's gx loads; consumed after B1 (dist ~ MFMA+gh write)
    const u16* src = gx_row + (size_t)t * (256 * H3_);
    u16x4 xr4 = *(const u16x4*)(src + col0);
    u16x4 xz4 = *(const u16x4*)(src + 256 + col0);
    u16x4 xn4 = *(const u16x4*)(src + 512 + col0);

    // B) gh^T = Wh^T * h^T (B-frag rows via r&7; cols r>=8 discarded)
    f32x4 acc[3][2];
    #pragma unroll
    for (int g = 0; g < 3; ++g)
      #pragma unroll
      for (int s = 0; s < 2; ++s)
        acc[g][s] = (f32x4){0.f, 0.f, 0.f, 0.f};

    #pragma unroll
    for (int kk = 0; kk < 8; ++kk) {
      bf16x8 hfrag = *(const bf16x8*)&h_bf[r & 7][kk * 32 + quad * 8];
      #pragma unroll
      for (int g = 0; g < 3; ++g)
        #pragma unroll
        for (int s = 0; s < 2; ++s)
          acc[g][s] = mfma16(bfr[g][s][kk], hfrag, acc[g][s]);
    }

    // gh tile: D[row=quad*4+e][col=r] = gh[batch=r][w*32+s*16+quad*4+e]
    if (r < 8) {
      #pragma unroll
      for (int g = 0; g < 3; ++g)
        #pragma unroll
        for (int s = 0; s < 2; ++s)
          *(f32x4*)&gh_lds[g][r][w * 32 + s * 16 + quad * 4] = acc[g][s];
    }
    __syncthreads();  // B1: gh visible; MFMA h_bf reads done

    // C) epilogue: thread (w, lane) -> batch row w, cols col0..+3
    {
      f32x4 gr = *(const f32x4*)&gh_lds[0][w][col0];
      f32x4 gz = *(const f32x4*)&gh_lds[1][w][col0];
      f32x4 gn = *(const f32x4*)&gh_lds[2][w][col0];
      u16x4 hw;
      #pragma unroll
      for (int e = 0; e < 4; ++e) {
        float sr = rcp_(1.f + exp2f_(-(bf2f(xr4[e]) + gr[e])));   // sigmoid
        float sz = rcp_(1.f + exp2f_(-(bf2f(xz4[e]) + gz[e])));
        float nv = bf2f(xn4[e]) + sr * (gn[e] + bhn[e]);          // 2*L2E-scaled
        float u  = exp2f_(-nv);
        float nn = fmaf(2.f, rcp_(1.f + u), -1.f);                // tanh, inf-safe
        float hv = nn + sz * (h_reg[e] - nn);
        h_reg[e] = hv;
        hw[e] = f2bf_fast(hv);
      }
      *(u16x4*)&h_bf[w][col0] = hw;
    }
    __syncthreads();  // B2: h ready for next step's MFMA
  }

  *(f32x4*)(hT + ((size_t)(c * 256 + b0 + w)) * 256 + col0) = h_reg;
}

// ---------------------------------------------------------------------------
// Kernel 4: out[b] = elu(sum_c hT[c,b,:] @ Wf + bf); feature[c,:] = mean_b hT
__global__ __launch_bounds__(128) void finalize(const float* __restrict__ hT,
                                                const float* __restrict__ Wf,
                                                const float* __restrict__ bfv,
                                                float* __restrict__ out) {
  __shared__ float hsum[256];
  const int bid = blockIdx.x, tid = threadIdx.x;
  if (bid < 256) {
    const int b = bid;
    for (int k = tid; k < 256; k += 128)
      hsum[k] = hT[((size_t)(0 * 256 + b)) * 256 + k]
              + hT[((size_t)(1 * 256 + b)) * 256 + k]
              + hT[((size_t)(2 * 256 + b)) * 256 + k];
    __syncthreads();
    float acc = bfv[tid];
    #pragma unroll 8
    for (int k = 0; k < 256; ++k)
      acc = fmaf(hsum[k], Wf[(size_t)k * OUT_ + tid], acc);
    float rv = acc > 0.f ? acc : (__expf(acc) - 1.f);
    out[b * OUT_ + tid] = rv;
  } else {
    const int idx = bid - 256;                 // 0..5
    const int c = idx >> 1, j = ((idx & 1) << 7) + tid;
    float sum = 0.f;
    #pragma unroll 4
    for (int b = 0; b < 256; ++b)
      sum += hT[((size_t)(c * 256 + b)) * 256 + j];
    out[B_ * OUT_ + c * 256 + j] = sum * (1.f / 256.f);
  }
}

// ---------------------------------------------------------------------------
extern "C" void kernel_launch(void* const* d_in, const int* in_sizes, int n_in,
                              void* d_out, int out_size, void* d_ws, size_t ws_size,
                              hipStream_t stream) {
  const float* x   = (const float*)d_in[0];
  const float* hid = (const float*)d_in[1];
  const float* Wx  = (const float*)d_in[2];
  const float* bx  = (const float*)d_in[3];
  const float* Wh  = (const float*)d_in[4];
  const float* bh  = (const float*)d_in[5];
  const float* Wf  = (const float*)d_in[6];
  const float* bf_ = (const float*)d_in[7];
  float* out = (float*)d_out;

  char* ws = (char*)d_ws;
  u16* WxT   = (u16*)ws;                                   // 768*128 bf16 = 192 KiB
  u16* gxw   = (u16*)(ws + (1 << 18));                     // 128*256*768 bf16 = 48 MiB
  float* hTw = (float*)(ws + (1 << 18) + (size_t)T_ * B_ * H3_ * 2);  // 3*256*256 f32

  wx_transpose<<<384, 256, 0, stream>>>(Wx, WxT);
  gx_gemm<<<dim3(256, 4), 512, 0, stream>>>(x, WxT, bx, bh, gxw);
  cru_scan<<<96, 512, 0, stream>>>(hid, Wh, bh, gxw, hTw);
  finalize<<<262, 128, 0, stream>>>(hTw, Wf, bf_, out);
}